// Round 4
// baseline (373.436 us; speedup 1.0000x reference)
//
#include <hip/hip_runtime.h>

// Problem constants
#define NB    16384   // batch
#define DIN   512     // dense in
#define NSP   26      // sparse embeddings
#define EMBD  128     // embedding dim
#define NOUT  512     // output dim
#define NI_   27      // NSP + 1
#define NTRI  378     // NI*(NI+1)/2
#define DOTK  890     // NTRI + DIN
#define KPAD  896     // DOTK padded to multiple of 64

typedef __attribute__((ext_vector_type(8)))  short bf16x8;  // 8 bf16 = 4 VGPRs
typedef __attribute__((ext_vector_type(4)))  float f32x4;   // MFMA 16x16 acc

// fp32 -> bf16 (RNE), bit-level
__device__ __forceinline__ short f2bf(float f) {
    unsigned u = __builtin_bit_cast(unsigned, f);
    unsigned r = (u + 0x7FFFu + ((u >> 16) & 1u)) >> 16;
    return (short)r;
}

__device__ __forceinline__ bf16x8 cvt8(float4 a, float4 b) {
    bf16x8 r;
    r[0] = f2bf(a.x); r[1] = f2bf(a.y); r[2] = f2bf(a.z); r[3] = f2bf(a.w);
    r[4] = f2bf(b.x); r[5] = f2bf(b.y); r[6] = f2bf(b.z); r[7] = f2bf(b.w);
    return r;
}

// async global -> LDS, 16 B per lane; lds dst is wave-uniform base (+lane*16 by HW)
__device__ __forceinline__ void gld_lds16(const void* g, void* l) {
    __builtin_amdgcn_global_load_lds((const __attribute__((address_space(1))) void*)g,
                                     (__attribute__((address_space(3))) void*)l,
                                     16, 0, 0);
}

// ---------------------------------------------------------------------------
// Prep (weights only now): Wo -> bf16 padded (512x896); Wp -> bf16.
// Dense conversion moved into gemm1_fused. ws re-poisoned each call.
// ---------------------------------------------------------------------------
#define WOP_N2   (NOUT * (KPAD / 8))  // 512*112 = 57,344
#define WPB_N2   (EMBD * DIN / 8)     // 8,192
__global__ __launch_bounds__(256) void prep_w_k(const float* __restrict__ Wo,
                                                const float* __restrict__ Wp,
                                                short* __restrict__ wop,
                                                short* __restrict__ wpb) {
    int idx = blockIdx.x * 256 + threadIdx.x;
    if (idx < WOP_N2) {
        int o = idx / (KPAD / 8), rem = idx - o * (KPAD / 8);
        int k = rem * 8;
        const float* src = Wo + (size_t)o * DOTK + k;
        bf16x8 r;
#pragma unroll
        for (int t = 0; t < 8; ++t) r[t] = (k + t < DOTK) ? f2bf(src[t]) : (short)0;
        *(bf16x8*)(wop + (size_t)o * KPAD + k) = r;
    } else {
        int j = idx - WOP_N2;
        if (j < WPB_N2) {
            const float4* p = (const float4*)(Wp + (size_t)j * 8);
            *(bf16x8*)(wpb + (size_t)j * 8) = cvt8(p[0], p[1]);
        }
    }
}

// ---------------------------------------------------------------------------
// gemm1_fused: dproj = dense @ Wp^T + bp  AND  zfb[:,0:512] = bf16(dense).
// BM=32, BN=128 (full N, single pass -> each (row,k) staged exactly once),
// BK=64, K=512. 256 threads = 4 waves (1x4), wave tile 32x32 (MT=2,NT=2).
// A-path: reg-staged (fp32 global -> cvt8 -> swizzled ds_write_b128) with the
// bf16x8 also stored to zfb (the prep side-output). B-path: gld_lds16 swizzled.
// 2-phase double-buffer: next tile's loads issued before current MFMAs; one
// __syncthreads per K-step drains vmcnt/lgkm. Numerics identical to split
// version (same f2bf, same MFMA k-order).
// ---------------------------------------------------------------------------
__global__ __launch_bounds__(256) void gemm1_fused(const float* __restrict__ dense,
                                                   const short* __restrict__ wpb,
                                                   const float* __restrict__ bp,
                                                   short* __restrict__ zfb,
                                                   short* __restrict__ dprojb) {
    __shared__ short As[2][32 * 64];    // 8 KB
    __shared__ short Bs[2][128 * 64];   // 32 KB

    const int tid = threadIdx.x;
    const int w = tid >> 6, l = tid & 63;
    const int r0 = l & 15, q = l >> 4;

    // bijective XCD swizzle (512 blocks, %8==0)
    const int nwg = (int)gridDim.x;
    const int bid = (int)blockIdx.x;
    const int swz = (bid & 7) * (nwg >> 3) + (bid >> 3);
    const int m0 = swz * 32;

    // A staging: thread t owns slot (row ar = t>>3, seg ag = t&7); 8 floats
    const int ar = tid >> 3, ag = tid & 7;
    const float* aptr = dense + (size_t)(m0 + ar) * DIN + ag * 8;
    short* zptr = zfb + (size_t)(m0 + ar) * KPAD + ag * 8;
    const int aoff = ar * 64 + (ag ^ (ar & 7)) * 8;   // swizzled LDS slot

    // B staging lane mapping: 8 rows x 8 segs per wave-instruction
    const int lr = l >> 3, pseg = l & 7;

    auto stageB = [&](int nb, int k0) {
#pragma unroll
        for (int i = 0; i < 4; ++i) {
            int r = w * 32 + i * 8 + lr;
            int ls = pseg ^ (r & 7);
            gld_lds16(wpb + (size_t)r * DIN + k0 + ls * 8,
                      (char*)&Bs[nb][0] + (w * 32 + i * 8) * 128);
        }
    };

    const f32x4 zero4 = {0.f, 0.f, 0.f, 0.f};
    f32x4 acc[2][2];
#pragma unroll
    for (int mi = 0; mi < 2; ++mi)
#pragma unroll
        for (int ni = 0; ni < 2; ++ni) acc[mi][ni] = zero4;

    // prologue: stage tile 0 (B async, A via regs), side-write zfb
    stageB(0, 0);
    {
        float4 a0 = *(const float4*)(aptr);
        float4 a1 = *(const float4*)(aptr + 4);
        bf16x8 av = cvt8(a0, a1);
        *(bf16x8*)&As[0][aoff] = av;
        *(bf16x8*)zptr = av;
    }
    __syncthreads();

    int cur = 0;
    for (int k = 0; k < 8; ++k) {
        const int k0 = k * 64;
        const bool pf = (k < 7);
        float4 n0, n1;
        if (pf) {
            stageB(cur ^ 1, k0 + 64);                 // B loads fly under MFMAs
            n0 = *(const float4*)(aptr + k0 + 64);    // A fp32 prefetch to regs
            n1 = *(const float4*)(aptr + k0 + 68);
        }

        __builtin_amdgcn_s_setprio(1);
#pragma unroll
        for (int h = 0; h < 2; ++h) {                 // two K=32 halves
            bf16x8 af[2], bfr[2];
#pragma unroll
            for (int mi = 0; mi < 2; ++mi) {
                int r = mi * 16 + r0;
                af[mi] = *(const bf16x8*)&As[cur][r * 64 + ((h * 4 + q) ^ (r & 7)) * 8];
            }
#pragma unroll
            for (int ni = 0; ni < 2; ++ni) {
                int r = w * 32 + ni * 16 + r0;
                bfr[ni] = *(const bf16x8*)&Bs[cur][r * 64 + ((h * 4 + q) ^ (r & 7)) * 8];
            }
#pragma unroll
            for (int mi = 0; mi < 2; ++mi)
#pragma unroll
                for (int ni = 0; ni < 2; ++ni)
                    acc[mi][ni] = __builtin_amdgcn_mfma_f32_16x16x32_bf16(
                        af[mi], bfr[ni], acc[mi][ni], 0, 0, 0);
        }
        __builtin_amdgcn_s_setprio(0);

        if (pf) {                                     // finish A stage for k+1
            bf16x8 av = cvt8(n0, n1);
            *(bf16x8*)&As[cur ^ 1][aoff] = av;
            *(bf16x8*)(zptr + k0 + 64) = av;          // prep side-output
        }
        __syncthreads();                              // drains vmcnt + guards bufs
        cur ^= 1;
    }

    // epilogue: C/D layout col=lane&15, row=(lane>>4)*4+reg  [m89/m91]
#pragma unroll
    for (int mi = 0; mi < 2; ++mi) {
#pragma unroll
        for (int ni = 0; ni < 2; ++ni) {
            int col = w * 32 + ni * 16 + r0;
            float bb = bp[col];
#pragma unroll
            for (int r = 0; r < 4; ++r) {
                int row = m0 + mi * 16 + q * 4 + r;
                dprojb[(size_t)row * EMBD + col] = f2bf(acc[mi][ni][r] + bb);
            }
        }
    }
}

// ---------------------------------------------------------------------------
// bf16 NT-GEMM via MFMA 16x16x32, BK=64: C[MxN] = A[Mxlda].rows(B[Nxldb]) + bias
// 2-phase dbuf pipeline, setprio around MFMA cluster, XOR-swizzled LDS,
// XCD-aware bijective block swizzle. See R3 notes.
// ---------------------------------------------------------------------------
template <int BM, int BN, bool OUTBF, int GXL2>
__global__ __launch_bounds__(256) void gemm_mfma(const short* __restrict__ A, int lda,
                                                 const short* __restrict__ Bm, int ldb,
                                                 const float* __restrict__ bias,
                                                 void* __restrict__ Cp, int ldc, int K) {
    constexpr int WM = BM / 2, WN = BN / 2;
    constexpr int MT = WM / 16, NT = WN / 16;
    __shared__ short As[2][BM * 64];
    __shared__ short Bs[2][BN * 64];

    const int tid = threadIdx.x;
    const int w = tid >> 6, l = tid & 63;
    const int wm = w >> 1, wn = w & 1;
    const int r0 = l & 15, q = l >> 4;

    const int nwg = (int)(gridDim.y << GXL2);
    const int bid = ((int)blockIdx.y << GXL2) | (int)blockIdx.x;
    const int swz = (bid & 7) * (nwg >> 3) + (bid >> 3);
    const int m0 = (swz >> GXL2) * BM;
    const int n0 = (swz & ((1 << GXL2) - 1)) * BN;

    const int lr = l >> 3, pseg = l & 7;

    auto stage = [&](int nb, int k0) {
#pragma unroll
        for (int i = 0; i < BM / 32; ++i) {
            int r = w * (BM / 4) + i * 8 + lr;
            int ls = pseg ^ (r & 7);
            gld_lds16(A + (size_t)(m0 + r) * lda + k0 + ls * 8,
                      (char*)&As[nb][0] + (w * (BM / 4) + i * 8) * 128);
        }
#pragma unroll
        for (int i = 0; i < BN / 32; ++i) {
            int r = w * (BN / 4) + i * 8 + lr;
            int ls = pseg ^ (r & 7);
            gld_lds16(Bm + (size_t)(n0 + r) * ldb + k0 + ls * 8,
                      (char*)&Bs[nb][0] + (w * (BN / 4) + i * 8) * 128);
        }
    };

    const f32x4 zero4 = {0.f, 0.f, 0.f, 0.f};
    f32x4 acc[MT][NT];
#pragma unroll
    for (int mi = 0; mi < MT; ++mi)
#pragma unroll
        for (int ni = 0; ni < NT; ++ni) acc[mi][ni] = zero4;

    stage(0, 0);
    __syncthreads();

    int cur = 0;
    for (int k0 = 0; k0 < K; k0 += 64) {
        if (k0 + 64 < K) stage(cur ^ 1, k0 + 64);
        const short* Ac = &As[cur][0];
        const short* Bc = &Bs[cur][0];

        __builtin_amdgcn_s_setprio(1);
#pragma unroll
        for (int h = 0; h < 2; ++h) {
            bf16x8 af[MT], bfr[NT];
#pragma unroll
            for (int mi = 0; mi < MT; ++mi) {
                int r = wm * WM + mi * 16 + r0;
                af[mi] = *(const bf16x8*)&Ac[r * 64 + ((h * 4 + q) ^ (r & 7)) * 8];
            }
#pragma unroll
            for (int ni = 0; ni < NT; ++ni) {
                int r = wn * WN + ni * 16 + r0;
                bfr[ni] = *(const bf16x8*)&Bc[r * 64 + ((h * 4 + q) ^ (r & 7)) * 8];
            }
#pragma unroll
            for (int mi = 0; mi < MT; ++mi)
#pragma unroll
                for (int ni = 0; ni < NT; ++ni)
                    acc[mi][ni] = __builtin_amdgcn_mfma_f32_16x16x32_bf16(
                        af[mi], bfr[ni], acc[mi][ni], 0, 0, 0);
        }
        __builtin_amdgcn_s_setprio(0);

        __syncthreads();
        cur ^= 1;
    }

#pragma unroll
    for (int mi = 0; mi < MT; ++mi) {
#pragma unroll
        for (int ni = 0; ni < NT; ++ni) {
            int col = n0 + wn * WN + ni * 16 + r0;
            float bb = bias[col];
#pragma unroll
            for (int r = 0; r < 4; ++r) {
                int row = m0 + wm * WM + mi * 16 + q * 4 + r;
                float v = acc[mi][ni][r] + bb;
                if (OUTBF) ((short*)Cp)[(size_t)row * ldc + col] = f2bf(v);
                else       ((float*)Cp)[(size_t)row * ldc + col] = v;
            }
        }
    }
}

// ---------------------------------------------------------------------------
// Interaction via MFMA: one wave per batch row. T = [dproj ; sparse] (27x128,
// zero-padded to 32). Gram = T.T^T with 16x16x32 MFMA; tril -> zfb[512:890] bf16,
// cols [890:896) zeroed. Wave-private LDS -> no __syncthreads needed.
// ---------------------------------------------------------------------------
__global__ __launch_bounds__(256) void interact_mfma(const float* __restrict__ sparse,
                                                     const short* __restrict__ dprojb,
                                                     short* __restrict__ zfb) {
    __shared__ short zt[4][384];   // 378 tril + 6 zero-pad, per wave
    const int w = threadIdx.x >> 6, l = threadIdx.x & 63;
    const int b = blockIdx.x * 4 + w;
    const int r0 = l & 15, q = l >> 4;

    const float* srow = sparse + (size_t)b * (NSP * EMBD);
    const short* dp = dprojb + (size_t)b * EMBD;

    const f32x4 zero4 = {0.f, 0.f, 0.f, 0.f};
    f32x4 acc00 = zero4, acc10 = zero4, acc11 = zero4;

#pragma unroll
    for (int kc = 0; kc < 4; ++kc) {
        int k = kc * 32 + q * 8;
        bf16x8 f0, f1;
        if (r0 == 0) {
            f0 = *(const bf16x8*)(dp + k);                  // T row 0 = dense_proj
        } else {
            const float* p = srow + (size_t)(r0 - 1) * EMBD + k;
            f0 = cvt8(*(const float4*)p, *(const float4*)(p + 4));
        }
        if (r0 <= 10) {                                     // T rows 16..26
            const float* p = srow + (size_t)(15 + r0) * EMBD + k;
            f1 = cvt8(*(const float4*)p, *(const float4*)(p + 4));
        } else {
            f1 = (bf16x8){0, 0, 0, 0, 0, 0, 0, 0};
        }
        acc00 = __builtin_amdgcn_mfma_f32_16x16x32_bf16(f0, f0, acc00, 0, 0, 0);
        acc10 = __builtin_amdgcn_mfma_f32_16x16x32_bf16(f1, f0, acc10, 0, 0, 0);
        acc11 = __builtin_amdgcn_mfma_f32_16x16x32_bf16(f1, f1, acc11, 0, 0, 0);
    }

    // scatter tril entries to LDS: row=(tile*16 + q*4 + r), col=(tile*16 + r0)
#pragma unroll
    for (int r = 0; r < 4; ++r) {
        int row, col;
        row = q * 4 + r;       col = r0;                    // tile (0,0)
        if (col <= row)             zt[w][row * (row + 1) / 2 + col] = f2bf(acc00[r]);
        row = 16 + q * 4 + r;  col = r0;                    // tile (1,0)
        if (row < NI_)              zt[w][row * (row + 1) / 2 + col] = f2bf(acc10[r]);
        /* tile (1,1) */       col = 16 + r0;
        if (row < NI_ && col <= row) zt[w][row * (row + 1) / 2 + col] = f2bf(acc11[r]);
    }
    // zero-pad tail (cols 890..895 of zfb row) and copy own row, 4B/lane
    if (l < 6) zt[w][NTRI + l] = 0;
    const int* zrow = (const int*)zt[w];
    int* dst = (int*)(zfb + (size_t)b * KPAD + DIN);
#pragma unroll
    for (int t = 0; t < 3; ++t) dst[t * 64 + l] = zrow[t * 64 + l];
}

// ---------------------------------------------------------------------------
extern "C" void kernel_launch(void* const* d_in, const int* in_sizes, int n_in,
                              void* d_out, int out_size, void* d_ws, size_t ws_size,
                              hipStream_t stream) {
    const float* dense  = (const float*)d_in[0];  // (16384, 512)
    const float* sparse = (const float*)d_in[1];  // (16384, 26, 128)
    const float* Wp     = (const float*)d_in[2];  // (128, 512)
    const float* bp     = (const float*)d_in[3];  // (128,)
    const float* Wo     = (const float*)d_in[4];  // (512, 890)
    const float* bo     = (const float*)d_in[5];  // (512,)
    float* out = (float*)d_out;                   // (16384, 512)

    short* zfb    = (short*)d_ws;                          // NB x 896 bf16
    short* dprojb = zfb + (size_t)NB * KPAD;               // NB x 128 bf16
    short* wop    = dprojb + (size_t)NB * EMBD;            // 512 x 896 bf16
    short* wpb    = wop + (size_t)NOUT * KPAD;             // 128 x 512 bf16

    // 1) weight conversions (tiny)
    prep_w_k<<<(WOP_N2 + WPB_N2) / 256, 256, 0, stream>>>(Wo, Wp, wop, wpb);

    // 2) dproj = dense @ Wp.T + bp, fused with dense->bf16 side-write to zfb
    gemm1_fused<<<NB / 32, 256, 0, stream>>>(dense, wpb, bp, zfb, dprojb);

    // 3) per-row Gram -> zfb[:, 512:896]
    interact_mfma<<<NB / 4, 256, 0, stream>>>(sparse, dprojb, zfb);

    // 4) out = Zflat @ Wo.T + bo  (M=16384, N=512, K=896), fp32 out; GXL2=2
    gemm_mfma<128, 128, false, 2><<<dim3(NOUT / 128, NB / 128), 256, 0, stream>>>(
        zfb, KPAD, wop, KPAD, bo, out, NOUT, KPAD);
}

// Round 5
// 371.120 us; speedup vs baseline: 1.0062x; 1.0062x over previous
//
#include <hip/hip_runtime.h>

// Problem constants
#define NB    16384   // batch
#define DIN   512     // dense in
#define NSP   26      // sparse embeddings
#define EMBD  128     // embedding dim
#define NOUT  512     // output dim
#define NI_   27      // NSP + 1
#define NTRI  378     // NI*(NI+1)/2
#define DOTK  890     // NTRI + DIN
#define KPAD  896     // DOTK padded to multiple of 64

typedef __attribute__((ext_vector_type(8)))  short bf16x8;  // 8 bf16 = 4 VGPRs
typedef __attribute__((ext_vector_type(4)))  float f32x4;   // MFMA 16x16 acc

// fp32 -> bf16 (RNE), bit-level
__device__ __forceinline__ short f2bf(float f) {
    unsigned u = __builtin_bit_cast(unsigned, f);
    unsigned r = (u + 0x7FFFu + ((u >> 16) & 1u)) >> 16;
    return (short)r;
}

__device__ __forceinline__ bf16x8 cvt8(float4 a, float4 b) {
    bf16x8 r;
    r[0] = f2bf(a.x); r[1] = f2bf(a.y); r[2] = f2bf(a.z); r[3] = f2bf(a.w);
    r[4] = f2bf(b.x); r[5] = f2bf(b.y); r[6] = f2bf(b.z); r[7] = f2bf(b.w);
    return r;
}

// async global -> LDS, 16 B per lane; lds dst is wave-uniform base (+lane*16 by HW)
__device__ __forceinline__ void gld_lds16(const void* g, void* l) {
    __builtin_amdgcn_global_load_lds((const __attribute__((address_space(1))) void*)g,
                                     (__attribute__((address_space(3))) void*)l,
                                     16, 0, 0);
}

// ---------------------------------------------------------------------------
// Merged prep, all paths 8-wide (16B stores):
//   dense fp32 -> bf16 into zfb[:,0:512]; Wo -> bf16 padded (512x896); Wp -> bf16.
// ws re-poisoned each call -> must rerun.
// ---------------------------------------------------------------------------
#define CONV_N2  (NB * 64)            // 8-float groups of dense (1,048,576)
#define WOP_N2   (NOUT * (KPAD / 8))  // 512*112 = 57,344
#define WPB_N2   (EMBD * DIN / 8)     // 8,192
__global__ __launch_bounds__(256) void prep_all_k(const float* __restrict__ dense,
                                                  const float* __restrict__ Wo,
                                                  const float* __restrict__ Wp,
                                                  short* __restrict__ zfb,
                                                  short* __restrict__ wop,
                                                  short* __restrict__ wpb) {
    int idx = blockIdx.x * 256 + threadIdx.x;
    if (idx < CONV_N2) {
        int b = idx >> 6, c = (idx & 63) * 8;
        const float4* p = (const float4*)(dense + (size_t)b * DIN + c);
        *(bf16x8*)(zfb + (size_t)b * KPAD + c) = cvt8(p[0], p[1]);
    } else if (idx < CONV_N2 + WOP_N2) {
        int j = idx - CONV_N2;
        int o = j / (KPAD / 8), rem = j - o * (KPAD / 8);
        int k = rem * 8;
        const float* src = Wo + (size_t)o * DOTK + k;
        bf16x8 r;
#pragma unroll
        for (int t = 0; t < 8; ++t) r[t] = (k + t < DOTK) ? f2bf(src[t]) : (short)0;
        *(bf16x8*)(wop + (size_t)o * KPAD + k) = r;
    } else {
        int j = idx - CONV_N2 - WOP_N2;
        if (j < WPB_N2) {
            const float4* p = (const float4*)(Wp + (size_t)j * 8);
            *(bf16x8*)(wpb + (size_t)j * 8) = cvt8(p[0], p[1]);
        }
    }
}

// ---------------------------------------------------------------------------
// bf16 NT-GEMM via MFMA 16x16x32, BK=64 (R1 structure, used for gemm1).
// Block: 256 threads = 4 waves (2x2), each wave (BM/2 x BN/2).
// gld_lds16 staging, XOR seg swizzle (seg ^= row&7), 2 barriers per K-step.
// GXL2 = log2(gridDim.x); XCD-aware bijective block swizzle.
// ---------------------------------------------------------------------------
template <int BM, int BN, bool OUTBF, int GXL2>
__global__ __launch_bounds__(256) void gemm_mfma(const short* __restrict__ A, int lda,
                                                 const short* __restrict__ Bm, int ldb,
                                                 const float* __restrict__ bias,
                                                 void* __restrict__ Cp, int ldc, int K) {
    constexpr int WM = BM / 2, WN = BN / 2;
    constexpr int MT = WM / 16, NT = WN / 16;
    __shared__ short As[BM * 64];
    __shared__ short Bs[BN * 64];

    const int tid = threadIdx.x;
    const int w = tid >> 6, l = tid & 63;
    const int wm = w >> 1, wn = w & 1;
    const int r0 = l & 15, q = l >> 4;

    const int nwg = (int)(gridDim.y << GXL2);
    const int bid = ((int)blockIdx.y << GXL2) | (int)blockIdx.x;
    const int swz = (bid & 7) * (nwg >> 3) + (bid >> 3);
    const int m0 = (swz >> GXL2) * BM;
    const int n0 = (swz & ((1 << GXL2) - 1)) * BN;

    const int lr = l >> 3, pseg = l & 7;

    const f32x4 zero4 = {0.f, 0.f, 0.f, 0.f};
    f32x4 acc[MT][NT];
#pragma unroll
    for (int mi = 0; mi < MT; ++mi)
#pragma unroll
        for (int ni = 0; ni < NT; ++ni) acc[mi][ni] = zero4;

    for (int k0 = 0; k0 < K; k0 += 64) {
#pragma unroll
        for (int i = 0; i < BM / 32; ++i) {
            int r = w * (BM / 4) + i * 8 + lr;
            int ls = pseg ^ (r & 7);
            gld_lds16(A + (size_t)(m0 + r) * lda + k0 + ls * 8,
                      (char*)As + (w * (BM / 4) + i * 8) * 128);
        }
#pragma unroll
        for (int i = 0; i < BN / 32; ++i) {
            int r = w * (BN / 4) + i * 8 + lr;
            int ls = pseg ^ (r & 7);
            gld_lds16(Bm + (size_t)(n0 + r) * ldb + k0 + ls * 8,
                      (char*)Bs + (w * (BN / 4) + i * 8) * 128);
        }
        __syncthreads();

#pragma unroll
        for (int h = 0; h < 2; ++h) {
            bf16x8 af[MT], bfr[NT];
#pragma unroll
            for (int mi = 0; mi < MT; ++mi) {
                int r = wm * WM + mi * 16 + r0;
                af[mi] = *(const bf16x8*)&As[r * 64 + ((h * 4 + q) ^ (r & 7)) * 8];
            }
#pragma unroll
            for (int ni = 0; ni < NT; ++ni) {
                int r = wn * WN + ni * 16 + r0;
                bfr[ni] = *(const bf16x8*)&Bs[r * 64 + ((h * 4 + q) ^ (r & 7)) * 8];
            }
#pragma unroll
            for (int mi = 0; mi < MT; ++mi)
#pragma unroll
                for (int ni = 0; ni < NT; ++ni)
                    acc[mi][ni] = __builtin_amdgcn_mfma_f32_16x16x32_bf16(
                        af[mi], bfr[ni], acc[mi][ni], 0, 0, 0);
        }
        __syncthreads();
    }

#pragma unroll
    for (int mi = 0; mi < MT; ++mi) {
#pragma unroll
        for (int ni = 0; ni < NT; ++ni) {
            int col = n0 + wn * WN + ni * 16 + r0;
            float bb = bias[col];
#pragma unroll
            for (int r = 0; r < 4; ++r) {
                int row = m0 + wm * WM + mi * 16 + q * 4 + r;
                float v = acc[mi][ni][r] + bb;
                if (OUTBF) ((short*)Cp)[(size_t)row * ldc + col] = f2bf(v);
                else       ((float*)Cp)[(size_t)row * ldc + col] = v;
            }
        }
    }
}

// ---------------------------------------------------------------------------
// gemm2_deep: out = zfb @ wop^T + bo  (M=16384, N=512, K=896), fp32 out.
// BM=256, BN=128, BK=64. 512 threads = 8 waves (4M x 2N), wave tile 64x64.
// Counted-vmcnt double-buffer (T4): vmcnt NEVER drains to 0 in the main loop;
// 6 gld_lds/thread per stage -> steady-state wait vmcnt(6) releases exactly
// the older buffer's group (vmcnt retires in order, m135). Raw s_barrier
// (no implicit drain) + sched_barrier(0) fences (rule #18). setprio around
// the MFMA cluster (T5: phase-split waves exist here). LDS 96KB, 1 block/CU.
// Grid 256 blocks (1-D, %8==0): XCD chunk swizzle -> each XCD's 32 blocks
// cover 8 m-panels x 4 n-tiles; A-panel (458KB x 8 = 3.7MB) fits its L2.
// ---------------------------------------------------------------------------
__global__ __launch_bounds__(512, 2) void gemm2_deep(const short* __restrict__ A,
                                                     const short* __restrict__ Bm,
                                                     const float* __restrict__ bias,
                                                     float* __restrict__ C) {
    __shared__ short As[2][256 * 64];   // 64 KB
    __shared__ short Bs[2][128 * 64];   // 32 KB

    const int tid = threadIdx.x;
    const int w = tid >> 6, l = tid & 63;
    const int wm = w >> 1, wn = w & 1;           // 4M x 2N
    const int r0 = l & 15, q = l >> 4;

    const int bid = (int)blockIdx.x;             // 256 blocks
    const int swz = (bid & 7) * 32 + (bid >> 3); // XCD chunk swizzle
    const int m0 = (swz >> 2) * 256;
    const int n0 = (swz & 3) * 128;

    const int lr = l >> 3, pseg = l & 7;

    // one stage = 6 gld_lds per thread (A: 4, B: 2)
    auto stage = [&](int nb, int k0) {
#pragma unroll
        for (int i = 0; i < 4; ++i) {            // A rows [w*32, w*32+32)
            int r = w * 32 + i * 8 + lr;
            int ls = pseg ^ (r & 7);
            gld_lds16(A + (size_t)(m0 + r) * KPAD + k0 + ls * 8,
                      (char*)&As[nb][0] + (w * 32 + i * 8) * 128);
        }
#pragma unroll
        for (int i = 0; i < 2; ++i) {            // B rows [w*16, w*16+16)
            int r = w * 16 + i * 8 + lr;
            int ls = pseg ^ (r & 7);
            gld_lds16(Bm + (size_t)(n0 + r) * KPAD + k0 + ls * 8,
                      (char*)&Bs[nb][0] + (w * 16 + i * 8) * 128);
        }
    };

    const f32x4 zero4 = {0.f, 0.f, 0.f, 0.f};
    f32x4 acc[4][4];
#pragma unroll
    for (int mi = 0; mi < 4; ++mi)
#pragma unroll
        for (int ni = 0; ni < 4; ++ni) acc[mi][ni] = zero4;

    // prologue: two tiles in flight (12 outstanding/thread)
    stage(0, 0);
    stage(1, 64);

    int cur = 0;
    constexpr int NK = KPAD / 64;                // 14
    for (int ks = 0; ks < NK; ++ks) {
        // release the OLDER group only (keep newest 6 in flight)
        if (ks < NK - 1) asm volatile("s_waitcnt vmcnt(6)" ::: "memory");
        else             asm volatile("s_waitcnt vmcnt(0)" ::: "memory");
        __builtin_amdgcn_s_barrier();            // all waves: buf[cur] ready
        __builtin_amdgcn_sched_barrier(0);       // no ds_read hoist above

        __builtin_amdgcn_s_setprio(1);
#pragma unroll
        for (int h = 0; h < 2; ++h) {
            bf16x8 af[4], bfr[4];
#pragma unroll
            for (int mi = 0; mi < 4; ++mi) {
                int r = wm * 64 + mi * 16 + r0;
                af[mi] = *(const bf16x8*)&As[cur][r * 64 + ((h * 4 + q) ^ (r & 7)) * 8];
            }
#pragma unroll
            for (int ni = 0; ni < 4; ++ni) {
                int r = wn * 64 + ni * 16 + r0;
                bfr[ni] = *(const bf16x8*)&Bs[cur][r * 64 + ((h * 4 + q) ^ (r & 7)) * 8];
            }
#pragma unroll
            for (int mi = 0; mi < 4; ++mi)
#pragma unroll
                for (int ni = 0; ni < 4; ++ni)
                    acc[mi][ni] = __builtin_amdgcn_mfma_f32_16x16x32_bf16(
                        af[mi], bfr[ni], acc[mi][ni], 0, 0, 0);
        }
        __builtin_amdgcn_s_setprio(0);

        // all lanes' ds_reads retired (MFMA consumption forces most already)
        asm volatile("s_waitcnt lgkmcnt(0)" ::: "memory");
        __builtin_amdgcn_s_barrier();            // all waves done reading buf[cur]
        __builtin_amdgcn_sched_barrier(0);

        if (ks + 2 < NK) stage(cur, (ks + 2) * 64);   // refill freed buffer
        cur ^= 1;
    }

    // epilogue: C/D layout col=lane&15, row=(lane>>4)*4+reg
#pragma unroll
    for (int mi = 0; mi < 4; ++mi) {
#pragma unroll
        for (int ni = 0; ni < 4; ++ni) {
            int col = n0 + wn * 64 + ni * 16 + r0;
            float bb = bias[col];
#pragma unroll
            for (int r = 0; r < 4; ++r) {
                int row = m0 + wm * 64 + mi * 16 + q * 4 + r;
                C[(size_t)row * NOUT + col] = acc[mi][ni][r] + bb;
            }
        }
    }
}

// ---------------------------------------------------------------------------
// Interaction via MFMA: one wave per batch row. T = [dproj ; sparse] (27x128,
// zero-padded to 32). Gram = T.T^T with 16x16x32 MFMA; tril -> zfb[512:890] bf16,
// cols [890:896) zeroed. Wave-private LDS -> no __syncthreads needed.
// ---------------------------------------------------------------------------
__global__ __launch_bounds__(256) void interact_mfma(const float* __restrict__ sparse,
                                                     const short* __restrict__ dprojb,
                                                     short* __restrict__ zfb) {
    __shared__ short zt[4][384];   // 378 tril + 6 zero-pad, per wave
    const int w = threadIdx.x >> 6, l = threadIdx.x & 63;
    const int b = blockIdx.x * 4 + w;
    const int r0 = l & 15, q = l >> 4;

    const float* srow = sparse + (size_t)b * (NSP * EMBD);
    const short* dp = dprojb + (size_t)b * EMBD;

    const f32x4 zero4 = {0.f, 0.f, 0.f, 0.f};
    f32x4 acc00 = zero4, acc10 = zero4, acc11 = zero4;

#pragma unroll
    for (int kc = 0; kc < 4; ++kc) {
        int k = kc * 32 + q * 8;
        bf16x8 f0, f1;
        if (r0 == 0) {
            f0 = *(const bf16x8*)(dp + k);                  // T row 0 = dense_proj
        } else {
            const float* p = srow + (size_t)(r0 - 1) * EMBD + k;
            f0 = cvt8(*(const float4*)p, *(const float4*)(p + 4));
        }
        if (r0 <= 10) {                                     // T rows 16..26
            const float* p = srow + (size_t)(15 + r0) * EMBD + k;
            f1 = cvt8(*(const float4*)p, *(const float4*)(p + 4));
        } else {
            f1 = (bf16x8){0, 0, 0, 0, 0, 0, 0, 0};
        }
        acc00 = __builtin_amdgcn_mfma_f32_16x16x32_bf16(f0, f0, acc00, 0, 0, 0);
        acc10 = __builtin_amdgcn_mfma_f32_16x16x32_bf16(f1, f0, acc10, 0, 0, 0);
        acc11 = __builtin_amdgcn_mfma_f32_16x16x32_bf16(f1, f1, acc11, 0, 0, 0);
    }

    // scatter tril entries to LDS: row=(tile*16 + q*4 + r), col=(tile*16 + r0)
#pragma unroll
    for (int r = 0; r < 4; ++r) {
        int row, col;
        row = q * 4 + r;       col = r0;                    // tile (0,0)
        if (col <= row)             zt[w][row * (row + 1) / 2 + col] = f2bf(acc00[r]);
        row = 16 + q * 4 + r;  col = r0;                    // tile (1,0)
        if (row < NI_)              zt[w][row * (row + 1) / 2 + col] = f2bf(acc10[r]);
        /* tile (1,1) */       col = 16 + r0;
        if (row < NI_ && col <= row) zt[w][row * (row + 1) / 2 + col] = f2bf(acc11[r]);
    }
    // zero-pad tail (cols 890..895 of zfb row) and copy own row, 4B/lane
    if (l < 6) zt[w][NTRI + l] = 0;
    const int* zrow = (const int*)zt[w];
    int* dst = (int*)(zfb + (size_t)b * KPAD + DIN);
#pragma unroll
    for (int t = 0; t < 3; ++t) dst[t * 64 + l] = zrow[t * 64 + l];
}

// ---------------------------------------------------------------------------
extern "C" void kernel_launch(void* const* d_in, const int* in_sizes, int n_in,
                              void* d_out, int out_size, void* d_ws, size_t ws_size,
                              hipStream_t stream) {
    const float* dense  = (const float*)d_in[0];  // (16384, 512)
    const float* sparse = (const float*)d_in[1];  // (16384, 26, 128)
    const float* Wp     = (const float*)d_in[2];  // (128, 512)
    const float* bp     = (const float*)d_in[3];  // (128,)
    const float* Wo     = (const float*)d_in[4];  // (512, 890)
    const float* bo     = (const float*)d_in[5];  // (512,)
    float* out = (float*)d_out;                   // (16384, 512)

    short* zfb    = (short*)d_ws;                          // NB x 896 bf16
    short* dprojb = zfb + (size_t)NB * KPAD;               // NB x 128 bf16
    short* wop    = dprojb + (size_t)NB * EMBD;            // 512 x 896 bf16
    short* wpb    = wop + (size_t)NOUT * KPAD;             // 128 x 512 bf16

    // 1) all conversions in one launch (8-wide)
    prep_all_k<<<(CONV_N2 + WOP_N2 + WPB_N2 + 255) / 256, 256, 0, stream>>>(
        dense, Wo, Wp, zfb, wop, wpb);

    // 2) dproj = dense @ Wp.T + bp  (M=16384, N=128, K=512), bf16 out; GXL2=1
    gemm_mfma<64, 64, true, 1><<<dim3(EMBD / 64, NB / 64), 256, 0, stream>>>(
        zfb, KPAD, wpb, DIN, bp, dprojb, EMBD, DIN);

    // 3) per-row Gram -> zfb[:, 512:896]
    interact_mfma<<<NB / 4, 256, 0, stream>>>(sparse, dprojb, zfb);

    // 4) out = Zflat @ Wo.T + bo: deep-pipelined 256x128 kernel, 1 block/CU
    gemm2_deep<<<256, 512, 0, stream>>>(zfb, wop, bo, out);
}